// Round 5
// baseline (220.093 us; speedup 1.0000x reference)
//
#include <hip/hip_runtime.h>
#include <hip/hip_bf16.h>

// Problem constants
#define BB    8
#define NNODE 128
#define CIN   512
#define HH    8
#define DDIM  64
#define HD    512   // H*D

typedef float f32x4 __attribute__((ext_vector_type(4)));
typedef short bf16x8 __attribute__((ext_vector_type(8)));

static __device__ __forceinline__ unsigned short f2bf(float f) {
    unsigned int x = __float_as_uint(f);
    x = x + 0x7FFFu + ((x >> 16) & 1u);
    return (unsigned short)(x >> 16);
}

static __device__ __forceinline__ bf16x8 pack8(f32x4 a, f32x4 b) {
    bf16x8 r;
    r[0] = (short)f2bf(a[0]); r[1] = (short)f2bf(a[1]);
    r[2] = (short)f2bf(a[2]); r[3] = (short)f2bf(a[3]);
    r[4] = (short)f2bf(b[0]); r[5] = (short)f2bf(b[1]);
    r[6] = (short)f2bf(b[2]); r[7] = (short)f2bf(b[3]);
    return r;
}

// ---------------------------------------------------------------------------
// Kernel 1: tiled transpose+convert Wq/Wk/Wv [c][hd] f32 -> WT [m][hd][c] bf16
// ---------------------------------------------------------------------------
__global__ __launch_bounds__(256) void k_wt(
    const float* __restrict__ Wq, const float* __restrict__ Wk,
    const float* __restrict__ Wv,
    unsigned short* __restrict__ WT)
{
    __shared__ unsigned short tile[64][72];
    const int cb = blockIdx.x;
    const int hb = blockIdx.y;
    const int m  = blockIdx.z;          // 0=Wq,1=Wk,2=Wv
    const float* W = (m == 0) ? Wq : (m == 1) ? Wk : Wv;
    const int t = threadIdx.x;

#pragma unroll
    for (int it = 0; it < 4; ++it) {
        int row = it * 16 + (t >> 4);
        int col = (t & 15) * 4;
        f32x4 v = *reinterpret_cast<const f32x4*>(W + (size_t)(cb * 64 + row) * HD + hb * 64 + col);
        tile[row][col + 0] = f2bf(v[0]);
        tile[row][col + 1] = f2bf(v[1]);
        tile[row][col + 2] = f2bf(v[2]);
        tile[row][col + 3] = f2bf(v[3]);
    }
    __syncthreads();

#pragma unroll
    for (int it = 0; it < 4; ++it) {
        int hd = it * 16 + (t >> 4);
        int c  = (t & 15) * 4;
        unsigned long long pk =
            (unsigned long long)(unsigned short)tile[c + 0][hd] |
            ((unsigned long long)(unsigned short)tile[c + 1][hd] << 16) |
            ((unsigned long long)(unsigned short)tile[c + 2][hd] << 32) |
            ((unsigned long long)(unsigned short)tile[c + 3][hd] << 48);
        *reinterpret_cast<unsigned long long*>(
            &WT[((size_t)(m + 1) * HD + hb * 64 + hd) * CIN + cb * 64 + c]) = pk;
    }
}

// ---------------------------------------------------------------------------
// Kernel 1b: We -> WT2 in MFMA-fragment-linear order.
// WT2: [h][cc][kt][dc][lane l][i0..7], 16B per lane slot.
// ---------------------------------------------------------------------------
__global__ __launch_bounds__(256) void k_wt2(
    const float* __restrict__ We, unsigned short* __restrict__ WT2)
{
    const int h  = blockIdx.x;          // 0..7
    const int cc = blockIdx.y;          // 0..3
    const int t  = threadIdx.x;
#pragma unroll
    for (int it = 0; it < 4; ++it) {
        int s  = it * 256 + t;          // 0..1023 = (kt,dc,l)
        int kt = s >> 8;
        int dc = (s >> 6) & 3;
        int l  = s & 63;
        int c0 = cc * 128 + kt * 32 + (l >> 4) * 8;
        int hd = h * 64 + dc * 16 + (l & 15);
        unsigned long long pk0 = 0, pk1 = 0;
#pragma unroll
        for (int i = 0; i < 4; ++i)
            pk0 |= (unsigned long long)f2bf(We[(size_t)(c0 + i) * HD + hd]) << (16 * i);
#pragma unroll
        for (int i = 0; i < 4; ++i)
            pk1 |= (unsigned long long)f2bf(We[(size_t)(c0 + 4 + i) * HD + hd]) << (16 * i);
        size_t off = ((((size_t)h * 4 + cc) * 4 + kt) * 4 + dc) * 512 + l * 8;
        *reinterpret_cast<unsigned long long*>(&WT2[off])     = pk0;
        *reinterpret_cast<unsigned long long*>(&WT2[off + 4]) = pk1;
    }
}

// ---------------------------------------------------------------------------
// Kernel 2: QKV projections via bf16 MFMA (unchanged).
// ---------------------------------------------------------------------------
__global__ __launch_bounds__(256) void k_qkv(
    const float* __restrict__ hin,
    const unsigned short* __restrict__ WT,
    const float* __restrict__ bq, const float* __restrict__ bk, const float* __restrict__ bv,
    float* __restrict__ Qo, float* __restrict__ Ko, float* __restrict__ Vo)
{
    __shared__ unsigned short hs[64][520];
    const int rt = blockIdx.x;
    const int ct = blockIdx.y;
    const int m  = blockIdx.z;
    const int t  = threadIdx.x;
    const int w  = t >> 6;
    const int l  = t & 63;
    const int g  = l >> 4;
    const int c15 = l & 15;
    const float* bias = (m == 0) ? bq : (m == 1) ? bk : bv;
    float* Out = (m == 0) ? Qo : (m == 1) ? Ko : Vo;
    const unsigned short* Wm = WT + (size_t)(m + 1) * HD * CIN;
    const int rowbase = rt * 64;
    const int colbase = ct * 64;

#pragma unroll
    for (int q = 0; q < 32; ++q) {
        int f = q * 1024 + t * 4;
        int row = f >> 9;
        int c = f & 511;
        f32x4 hv = *reinterpret_cast<const f32x4*>(hin + (size_t)(rowbase + row) * CIN + c);
        unsigned long long pk =
            (unsigned long long)f2bf(hv[0]) |
            ((unsigned long long)f2bf(hv[1]) << 16) |
            ((unsigned long long)f2bf(hv[2]) << 32) |
            ((unsigned long long)f2bf(hv[3]) << 48);
        *reinterpret_cast<unsigned long long*>(&hs[row][c]) = pk;
    }
    __syncthreads();

    f32x4 acc[4];
#pragma unroll
    for (int nf = 0; nf < 4; ++nf) acc[nf] = (f32x4){0.f, 0.f, 0.f, 0.f};

#pragma unroll
    for (int kt = 0; kt < 16; ++kt) {
        bf16x8 afr = *reinterpret_cast<const bf16x8*>(&hs[w * 16 + c15][kt * 32 + g * 8]);
#pragma unroll
        for (int nf = 0; nf < 4; ++nf) {
            const unsigned short* wp = Wm + (size_t)(colbase + nf * 16 + c15) * CIN + kt * 32 + g * 8;
            bf16x8 bfr = *reinterpret_cast<const bf16x8*>(wp);
            acc[nf] = __builtin_amdgcn_mfma_f32_16x16x32_bf16(afr, bfr, acc[nf], 0, 0, 0);
        }
    }

    const float scale = (m == 1) ? 0.125f : 1.0f;
#pragma unroll
    for (int nf = 0; nf < 4; ++nf) {
        int col = colbase + nf * 16 + c15;
        float bv_ = bias[col];
#pragma unroll
        for (int r = 0; r < 4; ++r) {
            int row = rowbase + w * 16 + g * 4 + r;
            Out[(size_t)row * HD + col] = (acc[nf][r] + bv_) * scale;
        }
    }
}

// ---------------------------------------------------------------------------
// Kernel 3: main fused kernel, v5 = r4 + vmcnt-FIFO fix:
// per chunk, ALL 16 B-fragment loads are issued BEFORE the staging loads
// (sched_barrier-pinned), so waiting on B never drains the HBM staging loads
// and the staging prefetch stays in flight across the whole MFMA phase.
// ---------------------------------------------------------------------------
__global__ __launch_bounds__(512, 3) void k_main(
    const float* __restrict__ e, const float* __restrict__ k_RW,
    const unsigned short* __restrict__ WT2,
    const float* __restrict__ be,
    const float* __restrict__ Qw, const float* __restrict__ Kw, const float* __restrict__ Vw,
    float* __restrict__ PN, float* __restrict__ PD)
{
    __shared__ unsigned short e_s[2][64 * 128];  // 2 x 16 KB, byte-swizzled
    __shared__ float s_lds[8][64];

    const int bx   = blockIdx.x;
    const int bi   = bx >> 1;         // b*128 + i
    const int half = bx & 1;
    const int b    = bi >> 7;
    const int t    = threadIdx.x;
    const int h    = t >> 6;          // wave id == head
    const int l    = t & 63;
    const int g    = l >> 4;
    const int c15  = l & 15;

    const int j0 = half * 64;
    const float* ebase = e + ((size_t)bi * NNODE + j0) * CIN;

    // staging map: thread t -> row t/8, 16 floats at col (t%8)*16
    const int srow = t >> 3;
    const int scg  = t & 7;
    const float* gsrc = ebase + (size_t)srow * CIN + scg * 16;
    const int xr  = (srow & 7) << 4;
    const int wb0 = srow * 256 + ((scg * 32) ^ xr);
    const int wb1 = srow * 256 + ((scg * 32 + 16) ^ xr);

    f32x4 acc[4][4];
#pragma unroll
    for (int jm = 0; jm < 4; ++jm)
#pragma unroll
        for (int dc = 0; dc < 4; ++dc)
            acc[jm][dc] = (f32x4){0.f, 0.f, 0.f, 0.f};

    // lane-fixed WT2 pointer: per (cc,kt,dc) a coalesced 16B slot at l*8
    const unsigned short* w2h = WT2 + (size_t)h * 32768 + l * 8;

    // prologue: stage chunk 0
    {
        f32x4 a0 = *reinterpret_cast<const f32x4*>(gsrc + 0);
        f32x4 a1 = *reinterpret_cast<const f32x4*>(gsrc + 4);
        f32x4 a2 = *reinterpret_cast<const f32x4*>(gsrc + 8);
        f32x4 a3 = *reinterpret_cast<const f32x4*>(gsrc + 12);
        char* base = (char*)&e_s[0][0];
        *reinterpret_cast<bf16x8*>(base + wb0) = pack8(a0, a1);
        *reinterpret_cast<bf16x8*>(base + wb1) = pack8(a2, a3);
    }
    __syncthreads();

    for (int cc = 0; cc < 4; ++cc) {
        const int buf = cc & 1;
        const char* rbase = (const char*)&e_s[buf][0];
        const unsigned short* bptr = w2h + cc * 8192;

        // (1) ALL B-fragment loads first (coalesced, L2-hot WT2)
        bf16x8 bfr[4][4];
#pragma unroll
        for (int kt = 0; kt < 4; ++kt)
#pragma unroll
            for (int dc = 0; dc < 4; ++dc)
                bfr[kt][dc] = *reinterpret_cast<const bf16x8*>(bptr + kt * 2048 + dc * 512);
        __builtin_amdgcn_sched_barrier(0);

        // (2) staging loads for chunk cc+1 — issued AFTER B (youngest in FIFO)
        f32x4 a0, a1, a2, a3;
        if (cc < 3) {
            const float* p = gsrc + (cc + 1) * 128;
            a0 = *reinterpret_cast<const f32x4*>(p + 0);
            a1 = *reinterpret_cast<const f32x4*>(p + 4);
            a2 = *reinterpret_cast<const f32x4*>(p + 8);
            a3 = *reinterpret_cast<const f32x4*>(p + 12);
        }
        __builtin_amdgcn_sched_barrier(0);

        // (3) MFMA phase: waits only on B (and LDS), staging stays in flight
#pragma unroll
        for (int kt = 0; kt < 4; ++kt) {
#pragma unroll
            for (int jm = 0; jm < 4; ++jm) {
                int row = jm * 16 + c15;
                int cb = (kt * 64 + g * 16) ^ ((row & 7) << 4);
                bf16x8 afr = *reinterpret_cast<const bf16x8*>(rbase + row * 256 + cb);
#pragma unroll
                for (int dc = 0; dc < 4; ++dc) {
                    acc[jm][dc] = __builtin_amdgcn_mfma_f32_16x16x32_bf16(afr, bfr[kt][dc], acc[jm][dc], 0, 0, 0);
                }
            }
        }

        // (4) pack + write next chunk (drains only the staging loads)
        if (cc < 3) {
            char* wbase = (char*)&e_s[buf ^ 1][0];
            *reinterpret_cast<bf16x8*>(wbase + wb0) = pack8(a0, a1);
            *reinterpret_cast<bf16x8*>(wbase + wb1) = pack8(a2, a3);
        }
        __syncthreads();
    }

    // ---- epilogue: scores for this wave's head, 64 local j ----
    const float* Kb  = Kw + (size_t)b * NNODE * HD;
    const float* krw = k_RW + (size_t)bi * NNODE + j0;
    float q_l[4], be_l[4];
#pragma unroll
    for (int dc = 0; dc < 4; ++dc) {
        q_l[dc]  = Qw[(size_t)bi * HD + h * 64 + dc * 16 + c15];
        be_l[dc] = be[h * 64 + dc * 16 + c15];
    }

#pragma unroll
    for (int jm = 0; jm < 4; ++jm) {
#pragma unroll
        for (int r = 0; r < 4; ++r) {
            int jl = jm * 16 + g * 4 + r;       // local j within half
            float sacc = 0.f;
#pragma unroll
            for (int dc = 0; dc < 4; ++dc) {
                float ev = acc[jm][dc][r] + be_l[dc];
                float kv = Kb[(size_t)(j0 + jl) * HD + h * 64 + dc * 16 + c15];
                sacc += ev * q_l[dc] * kv;
            }
            sacc += __shfl_xor(sacc, 1);
            sacc += __shfl_xor(sacc, 2);
            sacc += __shfl_xor(sacc, 4);
            sacc += __shfl_xor(sacc, 8);
            if (c15 == 0) {
                float sv = fminf(fmaxf(sacc, -5.f), 5.f);
                s_lds[h][jl] = __expf(sv) * krw[jl];
            }
        }
    }
    __syncthreads();

    // ---- PV partials: wave h, lane = d ----
    const float* Vb = Vw + (size_t)b * NNODE * HD;
    float o = 0.f, den = 0.f;
#pragma unroll 4
    for (int jl = 0; jl < 64; ++jl) {
        float sv = s_lds[h][jl];
        o = fmaf(sv, Vb[(size_t)(j0 + jl) * HD + h * 64 + l], o);
        den += sv;
    }
    PN[((size_t)bx * 8 + h) * 64 + l] = o;
    if (l == 0) PD[(size_t)bx * 8 + h] = den;
}

// ---------------------------------------------------------------------------
// Kernel 4: combine the two j-half partials and normalize.
// ---------------------------------------------------------------------------
__global__ __launch_bounds__(512) void k_norm(
    const float* __restrict__ PN, const float* __restrict__ PD,
    float* __restrict__ out)
{
    const int bi = blockIdx.x;
    const int t  = threadIdx.x;
    const int h  = t >> 6;
    const int d  = t & 63;
    size_t r0 = ((size_t)(bi * 2 + 0) * 8 + h);
    size_t r1 = ((size_t)(bi * 2 + 1) * 8 + h);
    float num = PN[r0 * 64 + d] + PN[r1 * 64 + d];
    float den = fmaxf(PD[r0] + PD[r1], 1e-6f);
    out[(size_t)bi * HD + h * 64 + d] = num / den;
}

// ---------------------------------------------------------------------------
extern "C" void kernel_launch(void* const* d_in, const int* in_sizes, int n_in,
                              void* d_out, int out_size, void* d_ws, size_t ws_size,
                              hipStream_t stream) {
    const float* hin = (const float*)d_in[0];
    const float* e   = (const float*)d_in[1];
    const float* krw = (const float*)d_in[2];
    const float* Wq  = (const float*)d_in[3];
    const float* bq  = (const float*)d_in[4];
    const float* Wk  = (const float*)d_in[5];
    const float* bk  = (const float*)d_in[6];
    const float* We  = (const float*)d_in[7];
    const float* be  = (const float*)d_in[8];
    const float* Wv  = (const float*)d_in[9];
    const float* bv  = (const float*)d_in[10];
    float* out = (float*)d_out;

    char* ws = (char*)d_ws;
    unsigned short* WT  = (unsigned short*)ws;                // 2 MB (slices 1..3 used)
    float* Q  = (float*)(ws + (2ull << 20));                  // 2 MB
    float* K  = (float*)(ws + (4ull << 20));                  // 2 MB
    float* V  = (float*)(ws + (6ull << 20));                  // 2 MB
    float* PN = (float*)(ws + (8ull << 20));                  // 4 MB
    float* PD = (float*)(ws + (12ull << 20));                 // 64 KB
    unsigned short* WT2 = (unsigned short*)(ws + (13ull << 20)); // 512 KB

    k_wt <<<dim3(8, 8, 3), dim3(256), 0, stream>>>(Wq, Wk, Wv, WT);
    k_wt2<<<dim3(8, 4),    dim3(256), 0, stream>>>(We, WT2);
    k_qkv<<<dim3(16, 8, 3), dim3(256), 0, stream>>>(hin, WT, bq, bk, bv, Q, K, V);
    k_main<<<dim3(2048), dim3(512), 0, stream>>>(e, krw, WT2, be, Q, K, V, PN, PD);
    k_norm<<<dim3(1024), dim3(512), 0, stream>>>(PN, PD, out);
}

// Round 6
// 187.492 us; speedup vs baseline: 1.1739x; 1.1739x over previous
//
#include <hip/hip_runtime.h>
#include <hip/hip_bf16.h>

// Problem constants
#define BB    8
#define NNODE 128
#define CIN   512
#define HH    8
#define DDIM  64
#define HD    512   // H*D

typedef float f32x4 __attribute__((ext_vector_type(4)));
typedef short bf16x8 __attribute__((ext_vector_type(8)));

#define AS1 __attribute__((address_space(1)))
#define AS3 __attribute__((address_space(3)))

static __device__ __forceinline__ unsigned short f2bf(float f) {
    unsigned int x = __float_as_uint(f);
    x = x + 0x7FFFu + ((x >> 16) & 1u);
    return (unsigned short)(x >> 16);
}
static __device__ __forceinline__ float bf2f(short u) {
    return __uint_as_float(((unsigned int)(unsigned short)u) << 16);
}
static __device__ __forceinline__ bf16x8 pack8(f32x4 a, f32x4 b) {
    bf16x8 r;
    r[0] = (short)f2bf(a[0]); r[1] = (short)f2bf(a[1]);
    r[2] = (short)f2bf(a[2]); r[3] = (short)f2bf(a[3]);
    r[4] = (short)f2bf(b[0]); r[5] = (short)f2bf(b[1]);
    r[6] = (short)f2bf(b[2]); r[7] = (short)f2bf(b[3]);
    return r;
}

// ---------------------------------------------------------------------------
// Kernel 1: tiled transpose+convert Wq/Wk/Wv [c][hd] f32 -> WT [m][hd][c] bf16
// (slices 1..3; for k_qkv).
// ---------------------------------------------------------------------------
__global__ __launch_bounds__(256) void k_wt(
    const float* __restrict__ Wq, const float* __restrict__ Wk,
    const float* __restrict__ Wv,
    unsigned short* __restrict__ WT)
{
    __shared__ unsigned short tile[64][72];
    const int cb = blockIdx.x;
    const int hb = blockIdx.y;
    const int m  = blockIdx.z;          // 0=Wq,1=Wk,2=Wv
    const float* W = (m == 0) ? Wq : (m == 1) ? Wk : Wv;
    const int t = threadIdx.x;

#pragma unroll
    for (int it = 0; it < 4; ++it) {
        int row = it * 16 + (t >> 4);
        int col = (t & 15) * 4;
        f32x4 v = *reinterpret_cast<const f32x4*>(W + (size_t)(cb * 64 + row) * HD + hb * 64 + col);
        tile[row][col + 0] = f2bf(v[0]);
        tile[row][col + 1] = f2bf(v[1]);
        tile[row][col + 2] = f2bf(v[2]);
        tile[row][col + 3] = f2bf(v[3]);
    }
    __syncthreads();

#pragma unroll
    for (int it = 0; it < 4; ++it) {
        int hd = it * 16 + (t >> 4);
        int c  = (t & 15) * 4;
        unsigned long long pk =
            (unsigned long long)(unsigned short)tile[c + 0][hd] |
            ((unsigned long long)(unsigned short)tile[c + 1][hd] << 16) |
            ((unsigned long long)(unsigned short)tile[c + 2][hd] << 32) |
            ((unsigned long long)(unsigned short)tile[c + 3][hd] << 48);
        *reinterpret_cast<unsigned long long*>(
            &WT[((size_t)(m + 1) * HD + hb * 64 + hd) * CIN + cb * 64 + c]) = pk;
    }
}

// ---------------------------------------------------------------------------
// Kernel 2: QKV projections via bf16 MFMA (unchanged).
// ---------------------------------------------------------------------------
__global__ __launch_bounds__(256) void k_qkv(
    const float* __restrict__ hin,
    const unsigned short* __restrict__ WT,
    const float* __restrict__ bq, const float* __restrict__ bk, const float* __restrict__ bv,
    float* __restrict__ Qo, float* __restrict__ Ko, float* __restrict__ Vo)
{
    __shared__ unsigned short hs[64][520];
    const int rt = blockIdx.x;
    const int ct = blockIdx.y;
    const int m  = blockIdx.z;
    const int t  = threadIdx.x;
    const int w  = t >> 6;
    const int l  = t & 63;
    const int g  = l >> 4;
    const int c15 = l & 15;
    const float* bias = (m == 0) ? bq : (m == 1) ? bk : bv;
    float* Out = (m == 0) ? Qo : (m == 1) ? Ko : Vo;
    const unsigned short* Wm = WT + (size_t)(m + 1) * HD * CIN;
    const int rowbase = rt * 64;
    const int colbase = ct * 64;

#pragma unroll
    for (int q = 0; q < 32; ++q) {
        int f = q * 1024 + t * 4;
        int row = f >> 9;
        int c = f & 511;
        f32x4 hv = *reinterpret_cast<const f32x4*>(hin + (size_t)(rowbase + row) * CIN + c);
        unsigned long long pk =
            (unsigned long long)f2bf(hv[0]) |
            ((unsigned long long)f2bf(hv[1]) << 16) |
            ((unsigned long long)f2bf(hv[2]) << 32) |
            ((unsigned long long)f2bf(hv[3]) << 48);
        *reinterpret_cast<unsigned long long*>(&hs[row][c]) = pk;
    }
    __syncthreads();

    f32x4 acc[4];
#pragma unroll
    for (int nf = 0; nf < 4; ++nf) acc[nf] = (f32x4){0.f, 0.f, 0.f, 0.f};

#pragma unroll
    for (int kt = 0; kt < 16; ++kt) {
        bf16x8 afr = *reinterpret_cast<const bf16x8*>(&hs[w * 16 + c15][kt * 32 + g * 8]);
#pragma unroll
        for (int nf = 0; nf < 4; ++nf) {
            const unsigned short* wp = Wm + (size_t)(colbase + nf * 16 + c15) * CIN + kt * 32 + g * 8;
            bf16x8 bfr = *reinterpret_cast<const bf16x8*>(wp);
            acc[nf] = __builtin_amdgcn_mfma_f32_16x16x32_bf16(afr, bfr, acc[nf], 0, 0, 0);
        }
    }

    const float scale = (m == 1) ? 0.125f : 1.0f;
#pragma unroll
    for (int nf = 0; nf < 4; ++nf) {
        int col = colbase + nf * 16 + c15;
        float bv_ = bias[col];
#pragma unroll
        for (int r = 0; r < 4; ++r) {
            int row = rowbase + w * 16 + g * 4 + r;
            Out[(size_t)row * HD + col] = (acc[nf][r] + bv_) * scale;
        }
    }
}

// ---------------------------------------------------------------------------
// Kernel 1c: We -> WT3, A-fragment-linear: m = c (lane&15), k = d.
// WT3[((h*8+ct)*4+mt)*2+kt][l][i] = bf16(We[ct*64+mt*16+(l&15)][h*64+kt*32+(l>>4)*8+i])
// ---------------------------------------------------------------------------
__global__ __launch_bounds__(256) void k_wt3(
    const float* __restrict__ We, unsigned short* __restrict__ WT3)
{
    const int h  = blockIdx.x;          // 0..7
    const int ct = blockIdx.y;          // 0..7
    const int t  = threadIdx.x;
#pragma unroll
    for (int it = 0; it < 2; ++it) {
        int s  = it * 256 + t;          // (mt,kt,l): 4*2*64 = 512
        int mt = s >> 7, kt = (s >> 6) & 1, l = s & 63;
        int c  = ct * 64 + mt * 16 + (l & 15);
        int hd = h * 64 + kt * 32 + (l >> 4) * 8;
        const float* src = We + (size_t)c * HD + hd;
        f32x4 v0 = *reinterpret_cast<const f32x4*>(src);
        f32x4 v1 = *reinterpret_cast<const f32x4*>(src + 4);
        size_t off = (((size_t)(h * 8 + ct) * 4 + mt) * 2 + kt) * 512 + l * 8;
        *reinterpret_cast<bf16x8*>(&WT3[off]) = pack8(v0, v1);
    }
}

// ---------------------------------------------------------------------------
// Kernel 1d: K (scaled, f32 from k_qkv) -> K2, B-fragment-linear: n = j, k = d.
// K2[((b*8+h)*2+kt)*8+nt][l][i] = bf16(Kw[b, nt*16+(l&15), h*64+kt*32+(l>>4)*8+i])
// ---------------------------------------------------------------------------
__global__ __launch_bounds__(256) void k_k2(
    const float* __restrict__ Kw, unsigned short* __restrict__ K2)
{
    const int b = blockIdx.x;           // 0..7
    const int h = blockIdx.y;           // 0..7
    const int t = threadIdx.x;
#pragma unroll
    for (int it = 0; it < 4; ++it) {
        int s  = it * 256 + t;          // (kt,nt,l): 2*8*64 = 1024
        int kt = s >> 9, nt = (s >> 6) & 7, l = s & 63;
        int j  = nt * 16 + (l & 15);
        int hd = h * 64 + kt * 32 + (l >> 4) * 8;
        const float* src = Kw + ((size_t)b * NNODE + j) * HD + hd;
        f32x4 v0 = *reinterpret_cast<const f32x4*>(src);
        f32x4 v1 = *reinterpret_cast<const f32x4*>(src + 4);
        size_t off = (((size_t)(b * 8 + h) * 2 + kt) * 8 + nt) * 512 + l * 8;
        *reinterpret_cast<bf16x8*>(&K2[off]) = pack8(v0, v1);
    }
}

// ---------------------------------------------------------------------------
// Kernel 3 v6: per block = (b,i). 512 thr = 8 waves, wave = head.
// scores[h,j] = sum_c e[j,c]*R[c,h,j] + sum_d be*Q*K,
// R = MFMA( A=We-frag (WT3), B'=bf16(Q.K) built from K2 ).
// e streamed f32 via global_load_lds, 4 buffers, counted vmcnt, XOR-swizzled.
// ---------------------------------------------------------------------------
__global__ __launch_bounds__(512, 4) void k_main(
    const float* __restrict__ e, const float* __restrict__ k_RW,
    const unsigned short* __restrict__ WT3, const unsigned short* __restrict__ K2,
    const float* __restrict__ be, const float* __restrict__ Qw,
    const float* __restrict__ Vw, float* __restrict__ out)
{
    __shared__ float e_s[4][4096];      // 4 x 16 KB tiles [jl 0..63][cl 0..63]
    __shared__ float s_lds[8][64];

    const int bx = blockIdx.x;
    const int bi = (bx & 7) * 128 + (bx >> 3);   // XCD-contiguous (1024 % 8 == 0)
    const int b  = bi >> 7;
    const int t  = threadIdx.x;
    const int h  = t >> 6;              // wave id == head
    const int l  = t & 63;
    const int g  = l >> 4;
    const int c15 = l & 15;

    const float* ebase = e + (size_t)bi * NNODE * CIN;

    // staging geometry: instr q of wave h covers rows jl = h*8+q*4 .. +3,
    // lane l writes dest byte = base + l*16  (row g, byte (l&15)*16).
    // read swizzle: word = jl*64 + (cl ^ ((jl&7)<<2))  => pre-swizzle the SOURCE.
    const int jl0 = h * 8 + g;          // q = 0
    const int jl1 = h * 8 + 4 + g;      // q = 1
    const int cb  = c15 * 16;           // dest byte within 256B row
    const int sc0 = (cb ^ ((jl0 & 7) << 4)) >> 2;   // source col (floats)
    const int sc1 = (cb ^ ((jl1 & 7) << 4)) >> 2;

    float o = 0.f, den = 0.f;
    bf16x8 Bp[2][4];

#define STAGE(TT) do {                                                          \
        const int jh_ = (TT) >> 3, ct_ = (TT) & 7, buf_ = (TT) & 3;             \
        const float* s0_ = ebase + (size_t)(jh_ * 64 + jl0) * CIN + ct_ * 64 + sc0; \
        const float* s1_ = ebase + (size_t)(jh_ * 64 + jl1) * CIN + ct_ * 64 + sc1; \
        char* l0_ = (char*)&e_s[0][0] + buf_ * 16384 + h * 2048;                \
        char* l1_ = l0_ + 1024;                                                 \
        __builtin_amdgcn_global_load_lds((const AS1 unsigned int*)s0_,          \
                                         (AS3 unsigned int*)l0_, 16, 0, 0);     \
        __builtin_amdgcn_global_load_lds((const AS1 unsigned int*)s1_,          \
                                         (AS3 unsigned int*)l1_, 16, 0, 0);     \
    } while (0)

    // prologue: 3 tiles in flight
    STAGE(0); STAGE(1); STAGE(2);

    for (int jh = 0; jh < 2; ++jh) {
        // ---- build B' = bf16(Q*K) from K2, fold bias term into score init ----
        float sc[4];
#pragma unroll
        for (int nt = 0; nt < 4; ++nt) sc[nt] = 0.f;
        {
            const unsigned short* k2b = K2 + ((size_t)(b * 8 + h) * 2) * 8 * 512 + l * 8;
#pragma unroll
            for (int kt = 0; kt < 2; ++kt) {
                const float* qp = Qw + (size_t)bi * HD + h * 64 + kt * 32 + g * 8;
                const float* bp_ = be + h * 64 + kt * 32 + g * 8;
                f32x4 qa = *reinterpret_cast<const f32x4*>(qp);
                f32x4 qb = *reinterpret_cast<const f32x4*>(qp + 4);
                f32x4 ba = *reinterpret_cast<const f32x4*>(bp_);
                f32x4 bb = *reinterpret_cast<const f32x4*>(bp_ + 4);
#pragma unroll
                for (int nt = 0; nt < 4; ++nt) {
                    bf16x8 kf = *reinterpret_cast<const bf16x8*>(
                        k2b + ((size_t)kt * 8 + jh * 4 + nt) * 512);
                    bf16x8 bpv;
                    float ab = 0.f;
#pragma unroll
                    for (int i = 0; i < 4; ++i) {
                        float p = bf2f(kf[i]) * qa[i];
                        bpv[i] = (short)f2bf(p);
                        ab = fmaf(ba[i], p, ab);
                    }
#pragma unroll
                    for (int i = 4; i < 8; ++i) {
                        float p = bf2f(kf[i]) * qb[i - 4];
                        bpv[i] = (short)f2bf(p);
                        ab = fmaf(bb[i - 4], p, ab);
                    }
                    Bp[kt][nt] = bpv;
                    sc[nt] += ab;
                }
            }
        }

        // ---- 8 c-tile phases ----
        for (int ct = 0; ct < 8; ++ct) {
            const int tt = jh * 8 + ct;
            if (tt < 14)       asm volatile("s_waitcnt vmcnt(4)" ::: "memory");
            else if (tt == 14) asm volatile("s_waitcnt vmcnt(2)" ::: "memory");
            else               asm volatile("s_waitcnt vmcnt(0)" ::: "memory");
            __builtin_amdgcn_sched_barrier(0);
            __builtin_amdgcn_s_barrier();
            __builtin_amdgcn_sched_barrier(0);
            if (tt < 13) STAGE(tt + 3);

            const float* ebuf = &e_s[tt & 3][0];
            const unsigned short* wt3 = WT3 + (size_t)(h * 8 + ct) * 8 * 512 + l * 8;
#pragma unroll
            for (int mt = 0; mt < 4; ++mt) {
                bf16x8 a0 = *reinterpret_cast<const bf16x8*>(wt3 + (mt * 2 + 0) * 512);
                bf16x8 a1 = *reinterpret_cast<const bf16x8*>(wt3 + (mt * 2 + 1) * 512);
                f32x4 D[4];
#pragma unroll
                for (int nt = 0; nt < 4; ++nt) {
                    f32x4 z = (f32x4){0.f, 0.f, 0.f, 0.f};
                    z = __builtin_amdgcn_mfma_f32_16x16x32_bf16(a0, Bp[0][nt], z, 0, 0, 0);
                    z = __builtin_amdgcn_mfma_f32_16x16x32_bf16(a1, Bp[1][nt], z, 0, 0, 0);
                    D[nt] = z;
                }
#pragma unroll
                for (int nt = 0; nt < 4; ++nt) {
                    int jl = nt * 16 + c15;
                    int cw = (mt * 16 + g * 4) ^ ((jl & 7) << 2);
                    f32x4 ev = *reinterpret_cast<const f32x4*>(ebuf + jl * 64 + cw);
                    sc[nt] += ev[0] * D[nt][0] + ev[1] * D[nt][1]
                            + ev[2] * D[nt][2] + ev[3] * D[nt][3];
                }
            }
        }

        // ---- finalize j-half: reduce, exp/clip/krw, PV ----
        const float* krw = k_RW + (size_t)bi * NNODE + jh * 64;
#pragma unroll
        for (int nt = 0; nt < 4; ++nt) {
            float s = sc[nt];
            s += __shfl_xor(s, 16);
            s += __shfl_xor(s, 32);
            float sv = __expf(fminf(fmaxf(s, -5.f), 5.f)) * krw[nt * 16 + c15];
            if (g == 0) s_lds[h][nt * 16 + c15] = sv;
        }
        asm volatile("s_waitcnt lgkmcnt(0)" ::: "memory");
        __builtin_amdgcn_sched_barrier(0);

        const float* Vb = Vw + ((size_t)b * NNODE + jh * 64) * HD + h * 64 + l;
#pragma unroll 4
        for (int jl = 0; jl < 64; ++jl) {
            float sv = s_lds[h][jl];
            o = fmaf(sv, Vb[(size_t)jl * HD], o);
            den += sv;
        }
    }
#undef STAGE

    out[(size_t)bi * HD + h * 64 + l] = o / fmaxf(den, 1e-6f);
}

// ---------------------------------------------------------------------------
extern "C" void kernel_launch(void* const* d_in, const int* in_sizes, int n_in,
                              void* d_out, int out_size, void* d_ws, size_t ws_size,
                              hipStream_t stream) {
    const float* hin = (const float*)d_in[0];
    const float* e   = (const float*)d_in[1];
    const float* krw = (const float*)d_in[2];
    const float* Wq  = (const float*)d_in[3];
    const float* bq  = (const float*)d_in[4];
    const float* Wk  = (const float*)d_in[5];
    const float* bk  = (const float*)d_in[6];
    const float* We  = (const float*)d_in[7];
    const float* be  = (const float*)d_in[8];
    const float* Wv  = (const float*)d_in[9];
    const float* bv  = (const float*)d_in[10];
    float* out = (float*)d_out;

    char* ws = (char*)d_ws;
    unsigned short* WT  = (unsigned short*)ws;                   // 2 MB (slices 1..3)
    float* Q  = (float*)(ws + (2ull << 20));                     // 2 MB
    float* K  = (float*)(ws + (4ull << 20));                     // 2 MB
    float* V  = (float*)(ws + (6ull << 20));                     // 2 MB
    unsigned short* WT3 = (unsigned short*)(ws + (8ull << 20));  // 512 KB
    unsigned short* K2  = (unsigned short*)(ws + (9ull << 20));  // 1 MB

    k_wt  <<<dim3(8, 8, 3), dim3(256), 0, stream>>>(Wq, Wk, Wv, WT);
    k_wt3 <<<dim3(8, 8),    dim3(256), 0, stream>>>(We, WT3);
    k_qkv <<<dim3(16, 8, 3), dim3(256), 0, stream>>>(hin, WT, bq, bk, bv, Q, K, V);
    k_k2  <<<dim3(8, 8),    dim3(256), 0, stream>>>(K, K2);
    k_main<<<dim3(1024), dim3(512), 0, stream>>>(e, krw, WT3, K2, be, Q, V, out);
}